// Round 6
// baseline (66571.967 us; speedup 1.0000x reference)
//
#include <hip/hip_runtime.h>

#define NS 1024
#define NH 64
#define NB 16384

// ---- XLA-CPU fp32 op clones (no FP contraction: __fmul_rn/__fadd_rn) ----

// Clone of XLA GenerateVF32Exp (Cephes/Eigen pexp, as in llvm_ir_runtime.cc)
__device__ __forceinline__ float xexp(float x) {
  x = fminf(x, 88.3762626647950f);
  x = fmaxf(x, -88.3762626647949f);
  float fx = floorf(__fadd_rn(__fmul_rn(x, 1.44269504088896341f), 0.5f));
  x = __fsub_rn(x, __fmul_rn(fx, 0.693359375f));
  x = __fsub_rn(x, __fmul_rn(fx, -2.12194440e-4f));
  float z = __fmul_rn(x, x);
  float y = 1.9875691500e-4f;
  y = __fadd_rn(__fmul_rn(y, x), 1.3981999507e-3f);
  y = __fadd_rn(__fmul_rn(y, x), 8.3334519073e-3f);
  y = __fadd_rn(__fmul_rn(y, x), 4.1665795894e-2f);
  y = __fadd_rn(__fmul_rn(y, x), 1.6666665459e-1f);
  y = __fadd_rn(__fmul_rn(y, x), 5.0000001201e-1f);
  y = __fadd_rn(__fmul_rn(y, z), x);
  y = __fadd_rn(y, 1.0f);
  int n = (int)fx;
  float p2n = __int_as_float((n + 127) << 23);
  return __fmul_rn(y, p2n);
}

// XLA logistic expansion: 1 / (1 + exp(-x)), IEEE divide
__device__ __forceinline__ float xsigmoid(float x) {
  float e = xexp(-x);
  return __fdiv_rn(1.0f, __fadd_rn(1.0f, e));
}

// Clone of XLA EmitFastTanh (Eigen ptanh rational approximation)
__device__ __forceinline__ float xtanh(float x) {
  float xc = fminf(fmaxf(x, -7.90531110763549805f), 7.90531110763549805f);
  float s = __fmul_rn(xc, xc);
  float p = -2.76076847742355e-16f;
  p = __fadd_rn(__fmul_rn(p, s), 2.00018790482477e-13f);
  p = __fadd_rn(__fmul_rn(p, s), -8.60467152213735e-11f);
  p = __fadd_rn(__fmul_rn(p, s), 5.12229709037114e-08f);
  p = __fadd_rn(__fmul_rn(p, s), 1.48572235717979e-05f);
  p = __fadd_rn(__fmul_rn(p, s), 6.37261928875436e-04f);
  p = __fadd_rn(__fmul_rn(p, s), 4.89352455891786e-03f);
  float num = __fmul_rn(xc, p);
  float q = 1.19825839466702e-06f;
  q = __fadd_rn(__fmul_rn(q, s), 1.18534705686654e-04f);
  q = __fadd_rn(__fmul_rn(q, s), 2.26843463243900e-03f);
  q = __fadd_rn(__fmul_rn(q, s), 4.89352518554385e-03f);
  float rat = __fdiv_rn(num, q);
  return (fabsf(x) < 0.0004f) ? x : rat;
}

// 4 waves/block, ONE row per wave. Lane j owns hidden unit j.
// Only w_r (64 floats) stays in VGPRs -> total live set ~100 < 128, so the
// RA needs NO AGPR round-trips (R1/R5's ~250-slot/step tax). w_z and w_n
// live in LDS, ONE 32KB copy shared by the block's 4 waves (fixes R5's
// hidden per-wave-block LDS duplication). DS stays under VALU: 32KB/wave-step
// x 16 waves/CU = 2048 cyc < ~2720 VALU cyc per window.
__global__ __launch_bounds__(256, 4) void gru_sample_kernel(
    const float* __restrict__ u, const float* __restrict__ w_ih,
    const float* __restrict__ w_hh, const float* __restrict__ b_ih,
    const float* __restrict__ b_hh, const float* __restrict__ head_w,
    const float* __restrict__ head_b, int* __restrict__ out) {
  const int lane = threadIdx.x & 63;
  const int wv = threadIdx.x >> 6;  // 0..3
  const int row = blockIdx.x * 4 + wv;

  __shared__ float4 wzq[16][NH];  // [k4][j] = w_z row j, k = 4k4..4k4+3
  __shared__ float4 wnq[16][NH];  // [k4][j] = w_n row j
  __shared__ float hbuf[4][NH];
  float* hb_ = hbuf[wv];

  // Cooperative fill: thread t -> unit j = t>>2, quarter q = t&3 (k4 = 4q..4q+3)
  {
    int j = threadIdx.x >> 2;
    int q = threadIdx.x & 3;
#pragma unroll
    for (int i = 0; i < 4; ++i) {
      int k4 = q * 4 + i;
      wzq[k4][j] = *(const float4*)&w_hh[(size_t)(64 + j) * NH + 4 * k4];
      wnq[k4][j] = *(const float4*)&w_hh[(size_t)(128 + j) * NH + 4 * k4];
    }
  }
  // r-gate weights in registers: w_hh[lane][k], k = 0..63
  float w_r[NH];
#pragma unroll
  for (int kq = 0; kq < 16; ++kq) {
    float4 a = *(const float4*)&w_hh[(size_t)lane * NH + kq * 4];
    w_r[kq * 4 + 0] = a.x; w_r[kq * 4 + 1] = a.y; w_r[kq * 4 + 2] = a.z; w_r[kq * 4 + 3] = a.w;
  }
  const float bih_r = b_ih[lane], bih_z = b_ih[64 + lane], bih_n = b_ih[128 + lane];
  const float bhh_r = b_hh[lane], bhh_z = b_hh[64 + lane], bhh_n = b_hh[128 + lane];
  // prev ∈ {0,1}: gx = prev*w_ih + b_ih == (prev ? w_ih+b_ih : b_ih) bit-exactly.
  const float sum_r = __fadd_rn(w_ih[lane], bih_r);
  const float sum_z = __fadd_rn(w_ih[64 + lane], bih_z);
  const float sum_n = __fadd_rn(w_ih[128 + lane], bih_n);
  const float hw = head_w[lane];
  const float hb = head_b[0];
  __syncthreads();  // weight LDS ready; waves independent after this

  const float* urow = u + (size_t)row * NS;
  int* orow = out + (size_t)row * NS;

  float h = 0.0f;
  int prev = 0;
  hb_[lane] = 0.0f;

  float u_cur = urow[lane];
  for (int c = 0; c < 16; ++c) {
    float u_next = (c < 15) ? urow[(c + 1) * 64 + lane] : 0.0f;
    int mybit = 0;
    for (int tt = 0; tt < 64; ++tt) {
      // gh = h @ w_hh.T : sequential-k FMA from 0 (Eigen gebp clone)
      float ar = 0.0f, az = 0.0f, an = 0.0f;
#pragma unroll
      for (int kq = 0; kq < 16; ++kq) {
        float4 hv = *(const float4*)&hb_[kq * 4];  // uniform-addr broadcast
        float4 wz = wzq[kq][lane];                 // lane-contiguous b128
        float4 wn = wnq[kq][lane];
        ar = fmaf(hv.x, w_r[kq * 4 + 0], ar);
        ar = fmaf(hv.y, w_r[kq * 4 + 1], ar);
        ar = fmaf(hv.z, w_r[kq * 4 + 2], ar);
        ar = fmaf(hv.w, w_r[kq * 4 + 3], ar);
        az = fmaf(hv.x, wz.x, az);
        az = fmaf(hv.y, wz.y, az);
        az = fmaf(hv.z, wz.z, az);
        az = fmaf(hv.w, wz.w, az);
        an = fmaf(hv.x, wn.x, an);
        an = fmaf(hv.y, wn.y, an);
        an = fmaf(hv.z, wn.z, an);
        an = fmaf(hv.w, wn.w, an);
      }
      // gates, exact reference association
      float gh_r = __fadd_rn(ar, bhh_r);
      float gh_z = __fadd_rn(az, bhh_z);
      float gh_n = __fadd_rn(an, bhh_n);
      float r = xsigmoid(__fadd_rn(prev ? sum_r : bih_r, gh_r));
      float z = xsigmoid(__fadd_rn(prev ? sum_z : bih_z, gh_z));
      float n = xtanh(__fadd_rn(prev ? sum_n : bih_n, __fmul_rn(r, gh_n)));
      h = __fadd_rn(__fmul_rn(__fsub_rn(1.0f, z), n), __fmul_rn(z, h));
      hb_[lane] = h;  // for next step's matvec (same-wave LDS, no barrier)

      // head gemv clone: width-16 chunks (mul + ordered adds), halving tree
      float P = __fmul_rn(h, hw);
      float s = __fadd_rn(P, __shfl(P, lane + 16));
      s = __fadd_rn(s, __shfl(P, lane + 32));
      s = __fadd_rn(s, __shfl(P, lane + 48));
      s = __fadd_rn(s, __shfl(s, lane + 8));
      s = __fadd_rn(s, __shfl(s, lane + 4));
      s = __fadd_rn(s, __shfl(s, lane + 2));
      s = __fadd_rn(s, __shfl(s, lane + 1));
      float logit = __fadd_rn(__shfl(s, 0), hb);
      float p = xsigmoid(logit);  // wave-uniform

      float u_t = __shfl(u_cur, tt);
      int b = (u_t < p) ? 1 : 0;
      prev = b;
      mybit = (lane == tt) ? b : mybit;
    }
    orow[c * 64 + lane] = mybit;  // coalesced per 64-step chunk
    u_cur = u_next;
  }
}

extern "C" void kernel_launch(void* const* d_in, const int* in_sizes, int n_in,
                              void* d_out, int out_size, void* d_ws, size_t ws_size,
                              hipStream_t stream) {
  const float* u = (const float*)d_in[0];
  const float* w_ih = (const float*)d_in[1];
  const float* w_hh = (const float*)d_in[2];
  const float* b_ih = (const float*)d_in[3];
  const float* b_hh = (const float*)d_in[4];
  const float* head_w = (const float*)d_in[5];
  const float* head_b = (const float*)d_in[6];
  int* out = (int*)d_out;
  dim3 grid(NB / 4), block(256);
  gru_sample_kernel<<<grid, block, 0, stream>>>(u, w_ih, w_hh, b_ih, b_hh,
                                                head_w, head_b, out);
}

// Round 7
// 17846.208 us; speedup vs baseline: 3.7303x; 3.7303x over previous
//
#include <hip/hip_runtime.h>

#define NS 1024
#define NH 64
#define NB 16384

typedef float f32x2 __attribute__((ext_vector_type(2)));
typedef float f32x4 __attribute__((ext_vector_type(4)));

// Disable FP contraction file-wide: vector a*b+c must stay mul+add (XLA-CPU
// has no contraction). Explicit fmaf / inline-asm pk_fma used where fma is
// intended.
#pragma clang fp contract(off)

// v_pk_fma_f32 with src1 broadcast from one register of its 64-bit pair.
// op_sel selects the source register for the LOW result half, op_sel_hi for
// the HIGH half (bits are [src0, src1, src2]).
// PKFMA_LO: both halves use w.lo ; PKFMA_HI: both halves use w.hi.
#define PKFMA_LO(acc, h, w)                                                  \
  asm("v_pk_fma_f32 %0, %1, %2, %0 op_sel:[0,0,0] op_sel_hi:[1,0,1]"         \
      : "+v"(acc) : "v"(h), "v"(w))
#define PKFMA_HI(acc, h, w)                                                  \
  asm("v_pk_fma_f32 %0, %1, %2, %0 op_sel:[0,1,0] op_sel_hi:[1,1,1]"         \
      : "+v"(acc) : "v"(h), "v"(w))

// ---- XLA-CPU fp32 op clones, packed over (rowA,rowB); per-component ops
// identical to the verified scalar clone (mul/add unfused, IEEE div). ----

__device__ __forceinline__ f32x2 xexp2v(f32x2 x) {
  x = __builtin_elementwise_min(x, f32x2{88.3762626647950f, 88.3762626647950f});
  x = __builtin_elementwise_max(x, f32x2{-88.3762626647949f, -88.3762626647949f});
  f32x2 fx = __builtin_elementwise_floor(x * 1.44269504088896341f + 0.5f);
  x = x - fx * 0.693359375f;
  x = x - fx * (-2.12194440e-4f);
  f32x2 z = x * x;
  f32x2 y = {1.9875691500e-4f, 1.9875691500e-4f};
  y = y * x + 1.3981999507e-3f;
  y = y * x + 8.3334519073e-3f;
  y = y * x + 4.1665795894e-2f;
  y = y * x + 1.6666665459e-1f;
  y = y * x + 5.0000001201e-1f;
  y = y * z + x;
  y = y + 1.0f;
  int n0 = (int)fx.x, n1 = (int)fx.y;
  float p0 = __int_as_float((n0 + 127) << 23);
  float p1 = __int_as_float((n1 + 127) << 23);
  f32x2 r;
  r.x = __fmul_rn(y.x, p0);
  r.y = __fmul_rn(y.y, p1);
  return r;
}

__device__ __forceinline__ f32x2 xsigmoid2(f32x2 x) {
  f32x2 e = xexp2v(-x);
  f32x2 d = e + 1.0f;
  f32x2 r;
  r.x = __fdiv_rn(1.0f, d.x);
  r.y = __fdiv_rn(1.0f, d.y);
  return r;
}

__device__ __forceinline__ f32x2 xtanh2(f32x2 x) {
  f32x2 xc = __builtin_elementwise_min(
      __builtin_elementwise_max(x, f32x2{-7.90531110763549805f, -7.90531110763549805f}),
      f32x2{7.90531110763549805f, 7.90531110763549805f});
  f32x2 s = xc * xc;
  f32x2 p = {-2.76076847742355e-16f, -2.76076847742355e-16f};
  p = p * s + 2.00018790482477e-13f;
  p = p * s + (-8.60467152213735e-11f);
  p = p * s + 5.12229709037114e-08f;
  p = p * s + 1.48572235717979e-05f;
  p = p * s + 6.37261928875436e-04f;
  p = p * s + 4.89352455891786e-03f;
  f32x2 num = xc * p;
  f32x2 q = {1.19825839466702e-06f, 1.19825839466702e-06f};
  q = q * s + 1.18534705686654e-04f;
  q = q * s + 2.26843463243900e-03f;
  q = q * s + 4.89352518554385e-03f;
  f32x2 rat;
  rat.x = __fdiv_rn(num.x, q.x);
  rat.y = __fdiv_rn(num.y, q.y);
  f32x2 r;
  r.x = (fabsf(x.x) < 0.0004f) ? x.x : rat.x;
  r.y = (fabsf(x.y) < 0.0004f) ? x.y : rat.y;
  return r;
}

__device__ __forceinline__ float rdlane(float v, int l) {
  return __int_as_float(__builtin_amdgcn_readlane(__float_as_int(v), l));
}

// 4 waves/block, TWO rows per wave via packed FP32 (v_pk_fma_f32): lane j
// owns hidden unit j for rows A,B. w_r in VGPRs as 32 f32x2 pairs (shared by
// both rows via op_sel broadcast - no duplication). w_z,w_n interleaved in
// LDS (one 32KB copy per block, read 32x ds_read_b128 per PAIR-step = half
// the per-row cost of R5). h stored as (hA,hB) pairs -> uniform b128 reads
// feed pk_fma directly. Live set ~120 < the 128-arch-VGPR cap (R2/R4/R6's
// spill killer). No barriers in the step loop (hp is wave-private).
__global__ __launch_bounds__(256, 2) void gru_sample_kernel(
    const float* __restrict__ u, const float* __restrict__ w_ih,
    const float* __restrict__ w_hh, const float* __restrict__ b_ih,
    const float* __restrict__ b_hh, const float* __restrict__ head_w,
    const float* __restrict__ head_b, int* __restrict__ out) {
  const int lane = threadIdx.x & 63;
  const int wv = threadIdx.x >> 6;  // 0..3
  const int rowA = blockIdx.x * 8 + wv * 2;
  const int rowB = rowA + 1;

  __shared__ f32x4 wzn[32][NH];   // [kk][j] = (wz[2kk], wn[2kk], wz[2kk+1], wn[2kk+1]) of unit j
  __shared__ f32x2 hp[4][NH];     // [wave][k] = (hA[k], hB[k])

  // Cooperative weight fill (one-time).
  for (int idx = threadIdx.x; idx < 32 * NH; idx += 256) {
    int kk = idx & 31, j = idx >> 5;
    const float* wzrow = w_hh + (size_t)(64 + j) * NH;
    const float* wnrow = w_hh + (size_t)(128 + j) * NH;
    wzn[kk][j] = f32x4{wzrow[2 * kk], wnrow[2 * kk], wzrow[2 * kk + 1], wnrow[2 * kk + 1]};
  }
  // r-gate weights in registers as pairs (wr[2i], wr[2i+1]).
  f32x2 wr2[32];
#pragma unroll
  for (int i = 0; i < 32; ++i)
    wr2[i] = *(const f32x2*)&w_hh[(size_t)lane * NH + 2 * i];

  const float bih_r = b_ih[lane], bih_z = b_ih[64 + lane], bih_n = b_ih[128 + lane];
  const float bhh_r = b_hh[lane], bhh_z = b_hh[64 + lane], bhh_n = b_hh[128 + lane];
  // prev ∈ {0,1}: gx = prev*w_ih + b_ih == (prev ? w_ih+b_ih : b_ih) bit-exactly.
  const float sum_r = __fadd_rn(w_ih[lane], bih_r);
  const float sum_z = __fadd_rn(w_ih[64 + lane], bih_z);
  const float sum_n = __fadd_rn(w_ih[128 + lane], bih_n);
  const float hwv = head_w[lane];
  const f32x2 hw2 = {hwv, hwv};
  const float hb = head_b[0];
  __syncthreads();  // weights ready; waves independent afterwards

  const float* urA = u + (size_t)rowA * NS;
  const float* urB = u + (size_t)rowB * NS;
  int* orA = out + (size_t)rowA * NS;
  int* orB = out + (size_t)rowB * NS;

  f32x2 h2 = {0.0f, 0.0f};
  int prevA = 0, prevB = 0;
  hp[wv][lane] = h2;
  const f32x4* hp4 = (const f32x4*)&hp[wv][0];

  for (int c = 0; c < 16; ++c) {
    float uA = urA[c * 64 + lane];
    float uB = urB[c * 64 + lane];
    int mybitA = 0, mybitB = 0;
    for (int tt = 0; tt < 64; ++tt) {
      // gh = h @ w_hh.T for both rows, packed: per-component sequential-k
      // FMA chain from 0 (Eigen gebp clone, components independent).
      f32x2 ar2 = {0.0f, 0.0f}, az2 = {0.0f, 0.0f}, an2 = {0.0f, 0.0f};
#pragma unroll 2
      for (int kk = 0; kk < 32; ++kk) {
        f32x4 h4 = hp4[kk];            // uniform b128: pairs for k=2kk, 2kk+1
        f32x4 w4 = wzn[kk][lane];      // lane-contiguous b128
        f32x2 h2a = __builtin_shufflevector(h4, h4, 0, 1);
        f32x2 h2b = __builtin_shufflevector(h4, h4, 2, 3);
        f32x2 wa = __builtin_shufflevector(w4, w4, 0, 1);  // (wz,wn) @ 2kk
        f32x2 wb = __builtin_shufflevector(w4, w4, 2, 3);  // (wz,wn) @ 2kk+1
        PKFMA_LO(ar2, h2a, wr2[kk]);   // += h * wr[2kk]
        PKFMA_LO(az2, h2a, wa);        // += h * wz[2kk]
        PKFMA_HI(an2, h2a, wa);        // += h * wn[2kk]
        PKFMA_HI(ar2, h2b, wr2[kk]);   // += h * wr[2kk+1]
        PKFMA_LO(az2, h2b, wb);        // += h * wz[2kk+1]
        PKFMA_HI(an2, h2b, wb);        // += h * wn[2kk+1]
      }
      // gates, exact reference association (packed mul/add are unfused)
      f32x2 ghr2 = ar2 + bhh_r;
      f32x2 ghz2 = az2 + bhh_z;
      f32x2 ghn2 = an2 + bhh_n;
      f32x2 gxr2 = {prevA ? sum_r : bih_r, prevB ? sum_r : bih_r};
      f32x2 gxz2 = {prevA ? sum_z : bih_z, prevB ? sum_z : bih_z};
      f32x2 gxn2 = {prevA ? sum_n : bih_n, prevB ? sum_n : bih_n};
      f32x2 r2 = xsigmoid2(gxr2 + ghr2);
      f32x2 z2 = xsigmoid2(gxz2 + ghz2);
      f32x2 n2 = xtanh2(gxn2 + r2 * ghn2);
      f32x2 omz = 1.0f - z2;           // (1-z): subrev, exact
      h2 = omz * n2 + z2 * h2;         // two muls + add, unfused = clone
      hp[wv][lane] = h2;               // for next step's matvec

      // head gemv clone: width-16 chunks then halving tree (per component)
      f32x2 P2 = h2 * hw2;
      f32x2 t, s2;
      t.x = __shfl(P2.x, lane + 16); t.y = __shfl(P2.y, lane + 16);
      s2 = P2 + t;
      t.x = __shfl(P2.x, lane + 32); t.y = __shfl(P2.y, lane + 32);
      s2 = s2 + t;
      t.x = __shfl(P2.x, lane + 48); t.y = __shfl(P2.y, lane + 48);
      s2 = s2 + t;
      t.x = __shfl(s2.x, lane + 8); t.y = __shfl(s2.y, lane + 8);
      s2 = s2 + t;
      t.x = __shfl(s2.x, lane + 4); t.y = __shfl(s2.y, lane + 4);
      s2 = s2 + t;
      t.x = __shfl(s2.x, lane + 2); t.y = __shfl(s2.y, lane + 2);
      s2 = s2 + t;
      t.x = __shfl(s2.x, lane + 1); t.y = __shfl(s2.y, lane + 1);
      s2 = s2 + t;
      float logitA = __fadd_rn(rdlane(s2.x, 0), hb);
      float logitB = __fadd_rn(rdlane(s2.y, 0), hb);
      f32x2 p2 = xsigmoid2(f32x2{logitA, logitB});

      float uAt = rdlane(uA, tt);
      float uBt = rdlane(uB, tt);
      int bA = (uAt < p2.x) ? 1 : 0;
      int bB = (uBt < p2.y) ? 1 : 0;
      prevA = bA;
      prevB = bB;
      mybitA = (lane == tt) ? bA : mybitA;
      mybitB = (lane == tt) ? bB : mybitB;
    }
    orA[c * 64 + lane] = mybitA;
    orB[c * 64 + lane] = mybitB;
  }
}

extern "C" void kernel_launch(void* const* d_in, const int* in_sizes, int n_in,
                              void* d_out, int out_size, void* d_ws, size_t ws_size,
                              hipStream_t stream) {
  const float* u = (const float*)d_in[0];
  const float* w_ih = (const float*)d_in[1];
  const float* w_hh = (const float*)d_in[2];
  const float* b_ih = (const float*)d_in[3];
  const float* b_hh = (const float*)d_in[4];
  const float* head_w = (const float*)d_in[5];
  const float* head_b = (const float*)d_in[6];
  int* out = (int*)d_out;
  dim3 grid(NB / 8), block(256);
  gru_sample_kernel<<<grid, block, 0, stream>>>(u, w_ih, w_hh, b_ih, b_hh,
                                                head_w, head_b, out);
}

// Round 8
// 8962.010 us; speedup vs baseline: 7.4282x; 1.9913x over previous
//
#include <hip/hip_runtime.h>

#define NS 1024
#define NH 64
#define NB 16384

typedef float f32x2 __attribute__((ext_vector_type(2)));
typedef float f32x4 __attribute__((ext_vector_type(4)));

// Disable FP contraction file-wide: vector a*b+c must stay mul+add (XLA-CPU
// has no contraction). Explicit inline-asm pk_fma used where fma is intended.
#pragma clang fp contract(off)

// v_pk_fma_f32 with src1 broadcast from one register of its 64-bit pair.
// op_sel selects the source register for the LOW result half, op_sel_hi for
// the HIGH half (bits are [src0, src1, src2]).
// PKFMA_LO: both halves use w.lo ; PKFMA_HI: both halves use w.hi.
// (Semantics HW-verified: R7 passed with absmax 0.0.)
#define PKFMA_LO(acc, h, w)                                                  \
  asm("v_pk_fma_f32 %0, %1, %2, %0 op_sel:[0,0,0] op_sel_hi:[1,0,1]"         \
      : "+v"(acc) : "v"(h), "v"(w))
#define PKFMA_HI(acc, h, w)                                                  \
  asm("v_pk_fma_f32 %0, %1, %2, %0 op_sel:[0,1,0] op_sel_hi:[1,1,1]"         \
      : "+v"(acc) : "v"(h), "v"(w))

// ---- XLA-CPU fp32 op clones, packed over (rowA,rowB); per-component ops
// identical to the verified scalar clone (mul/add unfused, IEEE div). ----

__device__ __forceinline__ f32x2 xexp2v(f32x2 x) {
  x = __builtin_elementwise_min(x, f32x2{88.3762626647950f, 88.3762626647950f});
  x = __builtin_elementwise_max(x, f32x2{-88.3762626647949f, -88.3762626647949f});
  f32x2 fx = __builtin_elementwise_floor(x * 1.44269504088896341f + 0.5f);
  x = x - fx * 0.693359375f;
  x = x - fx * (-2.12194440e-4f);
  f32x2 z = x * x;
  f32x2 y = {1.9875691500e-4f, 1.9875691500e-4f};
  y = y * x + 1.3981999507e-3f;
  y = y * x + 8.3334519073e-3f;
  y = y * x + 4.1665795894e-2f;
  y = y * x + 1.6666665459e-1f;
  y = y * x + 5.0000001201e-1f;
  y = y * z + x;
  y = y + 1.0f;
  int n0 = (int)fx.x, n1 = (int)fx.y;
  float p0 = __int_as_float((n0 + 127) << 23);
  float p1 = __int_as_float((n1 + 127) << 23);
  f32x2 r;
  r.x = __fmul_rn(y.x, p0);
  r.y = __fmul_rn(y.y, p1);
  return r;
}

__device__ __forceinline__ f32x2 xsigmoid2(f32x2 x) {
  f32x2 e = xexp2v(-x);
  f32x2 d = e + 1.0f;
  f32x2 r;
  r.x = __fdiv_rn(1.0f, d.x);
  r.y = __fdiv_rn(1.0f, d.y);
  return r;
}

__device__ __forceinline__ f32x2 xtanh2(f32x2 x) {
  f32x2 xc = __builtin_elementwise_min(
      __builtin_elementwise_max(x, f32x2{-7.90531110763549805f, -7.90531110763549805f}),
      f32x2{7.90531110763549805f, 7.90531110763549805f});
  f32x2 s = xc * xc;
  f32x2 p = {-2.76076847742355e-16f, -2.76076847742355e-16f};
  p = p * s + 2.00018790482477e-13f;
  p = p * s + (-8.60467152213735e-11f);
  p = p * s + 5.12229709037114e-08f;
  p = p * s + 1.48572235717979e-05f;
  p = p * s + 6.37261928875436e-04f;
  p = p * s + 4.89352455891786e-03f;
  f32x2 num = xc * p;
  f32x2 q = {1.19825839466702e-06f, 1.19825839466702e-06f};
  q = q * s + 1.18534705686654e-04f;
  q = q * s + 2.26843463243900e-03f;
  q = q * s + 4.89352518554385e-03f;
  f32x2 rat;
  rat.x = __fdiv_rn(num.x, q.x);
  rat.y = __fdiv_rn(num.y, q.y);
  f32x2 r;
  r.x = (fabsf(x.x) < 0.0004f) ? x.x : rat.x;
  r.y = (fabsf(x.y) < 0.0004f) ? x.y : rat.y;
  return r;
}

__device__ __forceinline__ float rdlane(float v, int l) {
  return __int_as_float(__builtin_amdgcn_readlane(__float_as_int(v), l));
}

// 4 waves/block, TWO rows per wave via packed FP32 (v_pk_fma_f32): lane j
// owns hidden unit j for rows A,B. w_r in VGPRs as 32 f32x2 pairs, accessed
// with COMPILE-TIME indices only (R7's #pragma unroll 2 made wr2[kk]
// runtime-indexed -> scratch -> 65 GB HBM, rule #20). Full unroll fixes it.
// w_z,w_n interleaved in LDS (one 32KB copy/block); h stored as (hA,hB)
// pairs -> uniform b128 reads feed pk_fma directly.
__global__ __launch_bounds__(256, 2) void gru_sample_kernel(
    const float* __restrict__ u, const float* __restrict__ w_ih,
    const float* __restrict__ w_hh, const float* __restrict__ b_ih,
    const float* __restrict__ b_hh, const float* __restrict__ head_w,
    const float* __restrict__ head_b, int* __restrict__ out) {
  const int lane = threadIdx.x & 63;
  const int wv = threadIdx.x >> 6;  // 0..3
  const int rowA = blockIdx.x * 8 + wv * 2;
  const int rowB = rowA + 1;

  __shared__ f32x4 wzn[32][NH];   // [kk][j] = (wz[2kk], wn[2kk], wz[2kk+1], wn[2kk+1]) of unit j
  __shared__ f32x2 hp[4][NH];     // [wave][k] = (hA[k], hB[k])

  // Cooperative weight fill (one-time).
  for (int idx = threadIdx.x; idx < 32 * NH; idx += 256) {
    int kk = idx & 31, j = idx >> 5;
    const float* wzrow = w_hh + (size_t)(64 + j) * NH;
    const float* wnrow = w_hh + (size_t)(128 + j) * NH;
    wzn[kk][j] = f32x4{wzrow[2 * kk], wnrow[2 * kk], wzrow[2 * kk + 1], wnrow[2 * kk + 1]};
  }
  // r-gate weights in registers as pairs (wr[2i], wr[2i+1]).
  f32x2 wr2[32];
#pragma unroll
  for (int i = 0; i < 32; ++i)
    wr2[i] = *(const f32x2*)&w_hh[(size_t)lane * NH + 2 * i];

  const float bih_r = b_ih[lane], bih_z = b_ih[64 + lane], bih_n = b_ih[128 + lane];
  const float bhh_r = b_hh[lane], bhh_z = b_hh[64 + lane], bhh_n = b_hh[128 + lane];
  // prev ∈ {0,1}: gx = prev*w_ih + b_ih == (prev ? w_ih+b_ih : b_ih) bit-exactly.
  const float sum_r = __fadd_rn(w_ih[lane], bih_r);
  const float sum_z = __fadd_rn(w_ih[64 + lane], bih_z);
  const float sum_n = __fadd_rn(w_ih[128 + lane], bih_n);
  const float hwv = head_w[lane];
  const f32x2 hw2 = {hwv, hwv};
  const float hb = head_b[0];
  __syncthreads();  // weights ready; waves independent afterwards

  const float* urA = u + (size_t)rowA * NS;
  const float* urB = u + (size_t)rowB * NS;
  int* orA = out + (size_t)rowA * NS;
  int* orB = out + (size_t)rowB * NS;

  f32x2 h2 = {0.0f, 0.0f};
  int prevA = 0, prevB = 0;
  hp[wv][lane] = h2;
  const f32x4* hp4 = (const f32x4*)&hp[wv][0];

  for (int c = 0; c < 16; ++c) {
    float uA = urA[c * 64 + lane];
    float uB = urB[c * 64 + lane];
    int mybitA = 0, mybitB = 0;
    for (int tt = 0; tt < 64; ++tt) {
      // gh = h @ w_hh.T for both rows, packed: per-component sequential-k
      // FMA chain from 0 (Eigen gebp clone, components independent).
      // FULL unroll: all wr2[] indices compile-time (keeps wr2 in VGPRs).
      f32x2 ar2 = {0.0f, 0.0f}, az2 = {0.0f, 0.0f}, an2 = {0.0f, 0.0f};
#pragma unroll
      for (int kk = 0; kk < 32; ++kk) {
        f32x4 h4 = hp4[kk];            // uniform b128: pairs for k=2kk, 2kk+1
        f32x4 w4 = wzn[kk][lane];      // lane-contiguous b128
        f32x2 h2a = __builtin_shufflevector(h4, h4, 0, 1);
        f32x2 h2b = __builtin_shufflevector(h4, h4, 2, 3);
        f32x2 wa = __builtin_shufflevector(w4, w4, 0, 1);  // (wz,wn) @ 2kk
        f32x2 wb = __builtin_shufflevector(w4, w4, 2, 3);  // (wz,wn) @ 2kk+1
        PKFMA_LO(ar2, h2a, wr2[kk]);   // += h * wr[2kk]
        PKFMA_LO(az2, h2a, wa);        // += h * wz[2kk]
        PKFMA_HI(an2, h2a, wa);        // += h * wn[2kk]
        PKFMA_HI(ar2, h2b, wr2[kk]);   // += h * wr[2kk+1]
        PKFMA_LO(az2, h2b, wb);        // += h * wz[2kk+1]
        PKFMA_HI(an2, h2b, wb);        // += h * wn[2kk+1]
      }
      // gates, exact reference association (packed mul/add are unfused)
      f32x2 ghr2 = ar2 + bhh_r;
      f32x2 ghz2 = az2 + bhh_z;
      f32x2 ghn2 = an2 + bhh_n;
      f32x2 gxr2 = {prevA ? sum_r : bih_r, prevB ? sum_r : bih_r};
      f32x2 gxz2 = {prevA ? sum_z : bih_z, prevB ? sum_z : bih_z};
      f32x2 gxn2 = {prevA ? sum_n : bih_n, prevB ? sum_n : bih_n};
      f32x2 r2 = xsigmoid2(gxr2 + ghr2);
      f32x2 z2 = xsigmoid2(gxz2 + ghz2);
      f32x2 n2 = xtanh2(gxn2 + r2 * ghn2);
      f32x2 omz = 1.0f - z2;           // (1-z): subrev, exact
      h2 = omz * n2 + z2 * h2;         // two muls + add, unfused = clone
      hp[wv][lane] = h2;               // for next step's matvec

      // head gemv clone: width-16 chunks then halving tree (per component)
      f32x2 P2 = h2 * hw2;
      f32x2 t, s2;
      t.x = __shfl(P2.x, lane + 16); t.y = __shfl(P2.y, lane + 16);
      s2 = P2 + t;
      t.x = __shfl(P2.x, lane + 32); t.y = __shfl(P2.y, lane + 32);
      s2 = s2 + t;
      t.x = __shfl(P2.x, lane + 48); t.y = __shfl(P2.y, lane + 48);
      s2 = s2 + t;
      t.x = __shfl(s2.x, lane + 8); t.y = __shfl(s2.y, lane + 8);
      s2 = s2 + t;
      t.x = __shfl(s2.x, lane + 4); t.y = __shfl(s2.y, lane + 4);
      s2 = s2 + t;
      t.x = __shfl(s2.x, lane + 2); t.y = __shfl(s2.y, lane + 2);
      s2 = s2 + t;
      t.x = __shfl(s2.x, lane + 1); t.y = __shfl(s2.y, lane + 1);
      s2 = s2 + t;
      float logitA = __fadd_rn(rdlane(s2.x, 0), hb);
      float logitB = __fadd_rn(rdlane(s2.y, 0), hb);
      f32x2 p2 = xsigmoid2(f32x2{logitA, logitB});

      float uAt = rdlane(uA, tt);
      float uBt = rdlane(uB, tt);
      int bA = (uAt < p2.x) ? 1 : 0;
      int bB = (uBt < p2.y) ? 1 : 0;
      prevA = bA;
      prevB = bB;
      mybitA = (lane == tt) ? bA : mybitA;
      mybitB = (lane == tt) ? bB : mybitB;
    }
    orA[c * 64 + lane] = mybitA;
    orB[c * 64 + lane] = mybitB;
  }
}

extern "C" void kernel_launch(void* const* d_in, const int* in_sizes, int n_in,
                              void* d_out, int out_size, void* d_ws, size_t ws_size,
                              hipStream_t stream) {
  const float* u = (const float*)d_in[0];
  const float* w_ih = (const float*)d_in[1];
  const float* w_hh = (const float*)d_in[2];
  const float* b_ih = (const float*)d_in[3];
  const float* b_hh = (const float*)d_in[4];
  const float* head_w = (const float*)d_in[5];
  const float* head_b = (const float*)d_in[6];
  int* out = (int*)d_out;
  dim3 grid(NB / 8), block(256);
  gru_sample_kernel<<<grid, block, 0, stream>>>(u, w_ih, w_hh, b_ih, b_hh,
                                                head_w, head_b, out);
}

// Round 9
// 8849.924 us; speedup vs baseline: 7.5223x; 1.0127x over previous
//
#include <hip/hip_runtime.h>

#define NS 1024
#define NH 64
#define NB 16384

typedef float f32x2 __attribute__((ext_vector_type(2)));
typedef float f32x4 __attribute__((ext_vector_type(4)));

// Disable FP contraction file-wide: vector a*b+c must stay mul+add (XLA-CPU
// has no contraction). Explicit inline-asm pk_fma used where fma is intended.
#pragma clang fp contract(off)

// v_pk_fma_f32 with src1 broadcast from one register of its 64-bit pair.
// op_sel selects the source register for the LOW result half, op_sel_hi for
// the HIGH half (bits are [src0, src1, src2]).
// PKFMA_LO: both halves use w.lo ; PKFMA_HI: both halves use w.hi.
// (Semantics HW-verified: R7/R8 passed with absmax 0.0.)
#define PKFMA_LO(acc, h, w)                                                  \
  asm("v_pk_fma_f32 %0, %1, %2, %0 op_sel:[0,0,0] op_sel_hi:[1,0,1]"         \
      : "+v"(acc) : "v"(h), "v"(w))
#define PKFMA_HI(acc, h, w)                                                  \
  asm("v_pk_fma_f32 %0, %1, %2, %0 op_sel:[0,1,0] op_sel_hi:[1,1,1]"         \
      : "+v"(acc) : "v"(h), "v"(w))

// ---- XLA-CPU fp32 op clones, packed over (rowA,rowB); per-component ops
// identical to the verified scalar clone (mul/add unfused, IEEE div). ----

__device__ __forceinline__ f32x2 xexp2v(f32x2 x) {
  x = __builtin_elementwise_min(x, f32x2{88.3762626647950f, 88.3762626647950f});
  x = __builtin_elementwise_max(x, f32x2{-88.3762626647949f, -88.3762626647949f});
  f32x2 fx = __builtin_elementwise_floor(x * 1.44269504088896341f + 0.5f);
  x = x - fx * 0.693359375f;
  x = x - fx * (-2.12194440e-4f);
  f32x2 z = x * x;
  f32x2 y = {1.9875691500e-4f, 1.9875691500e-4f};
  y = y * x + 1.3981999507e-3f;
  y = y * x + 8.3334519073e-3f;
  y = y * x + 4.1665795894e-2f;
  y = y * x + 1.6666665459e-1f;
  y = y * x + 5.0000001201e-1f;
  y = y * z + x;
  y = y + 1.0f;
  int n0 = (int)fx.x, n1 = (int)fx.y;
  float p0 = __int_as_float((n0 + 127) << 23);
  float p1 = __int_as_float((n1 + 127) << 23);
  f32x2 r;
  r.x = __fmul_rn(y.x, p0);
  r.y = __fmul_rn(y.y, p1);
  return r;
}

__device__ __forceinline__ f32x2 xsigmoid2(f32x2 x) {
  f32x2 e = xexp2v(-x);
  f32x2 d = e + 1.0f;
  f32x2 r;
  r.x = __fdiv_rn(1.0f, d.x);
  r.y = __fdiv_rn(1.0f, d.y);
  return r;
}

__device__ __forceinline__ f32x2 xtanh2(f32x2 x) {
  f32x2 xc = __builtin_elementwise_min(
      __builtin_elementwise_max(x, f32x2{-7.90531110763549805f, -7.90531110763549805f}),
      f32x2{7.90531110763549805f, 7.90531110763549805f});
  f32x2 s = xc * xc;
  f32x2 p = {-2.76076847742355e-16f, -2.76076847742355e-16f};
  p = p * s + 2.00018790482477e-13f;
  p = p * s + (-8.60467152213735e-11f);
  p = p * s + 5.12229709037114e-08f;
  p = p * s + 1.48572235717979e-05f;
  p = p * s + 6.37261928875436e-04f;
  p = p * s + 4.89352455891786e-03f;
  f32x2 num = xc * p;
  f32x2 q = {1.19825839466702e-06f, 1.19825839466702e-06f};
  q = q * s + 1.18534705686654e-04f;
  q = q * s + 2.26843463243900e-03f;
  q = q * s + 4.89352518554385e-03f;
  f32x2 rat;
  rat.x = __fdiv_rn(num.x, q.x);
  rat.y = __fdiv_rn(num.y, q.y);
  f32x2 r;
  r.x = (fabsf(x.x) < 0.0004f) ? x.x : rat.x;
  r.y = (fabsf(x.y) < 0.0004f) ? x.y : rat.y;
  return r;
}

__device__ __forceinline__ float rdlane(float v, int l) {
  return __int_as_float(__builtin_amdgcn_readlane(__float_as_int(v), l));
}

// 4 waves/block, TWO rows per wave via packed FP32 (v_pk_fma_f32): lane j
// owns hidden unit j for rows A,B. w_r in VGPRs as 32 f32x2 pairs (all
// indices compile-time). w_z,w_n interleaved in LDS (one 32KB copy/block);
// h stored as (hA,hB) pairs -> uniform b128 reads feed pk_fma directly.
// __launch_bounds__(256, 1): R8's (256,2) made the RA split the ~136-reg
// live set as 72 VGPR + 64 AGPR -> ~550 issue-slots/step of accvgpr/mov tax.
// min-waves=1 raises the arch-VGPR ceiling to 256 so everything lives in
// true VGPRs; occupancy self-sets (~3 waves/SIMD) from actual usage.
__global__ __launch_bounds__(256, 1) void gru_sample_kernel(
    const float* __restrict__ u, const float* __restrict__ w_ih,
    const float* __restrict__ w_hh, const float* __restrict__ b_ih,
    const float* __restrict__ b_hh, const float* __restrict__ head_w,
    const float* __restrict__ head_b, int* __restrict__ out) {
  const int lane = threadIdx.x & 63;
  const int wv = threadIdx.x >> 6;  // 0..3
  const int rowA = blockIdx.x * 8 + wv * 2;
  const int rowB = rowA + 1;

  __shared__ f32x4 wzn[32][NH];   // [kk][j] = (wz[2kk], wn[2kk], wz[2kk+1], wn[2kk+1]) of unit j
  __shared__ f32x2 hp[4][NH];     // [wave][k] = (hA[k], hB[k])

  // Cooperative weight fill (one-time).
  for (int idx = threadIdx.x; idx < 32 * NH; idx += 256) {
    int kk = idx & 31, j = idx >> 5;
    const float* wzrow = w_hh + (size_t)(64 + j) * NH;
    const float* wnrow = w_hh + (size_t)(128 + j) * NH;
    wzn[kk][j] = f32x4{wzrow[2 * kk], wnrow[2 * kk], wzrow[2 * kk + 1], wnrow[2 * kk + 1]};
  }
  // r-gate weights in registers as pairs (wr[2i], wr[2i+1]).
  f32x2 wr2[32];
#pragma unroll
  for (int i = 0; i < 32; ++i)
    wr2[i] = *(const f32x2*)&w_hh[(size_t)lane * NH + 2 * i];

  const float bih_r = b_ih[lane], bih_z = b_ih[64 + lane], bih_n = b_ih[128 + lane];
  const float bhh_r = b_hh[lane], bhh_z = b_hh[64 + lane], bhh_n = b_hh[128 + lane];
  // prev ∈ {0,1}: gx = prev*w_ih + b_ih == (prev ? w_ih+b_ih : b_ih) bit-exactly.
  const float sum_r = __fadd_rn(w_ih[lane], bih_r);
  const float sum_z = __fadd_rn(w_ih[64 + lane], bih_z);
  const float sum_n = __fadd_rn(w_ih[128 + lane], bih_n);
  const float hwv = head_w[lane];
  const f32x2 hw2 = {hwv, hwv};
  const float hb = head_b[0];
  __syncthreads();  // weights ready; waves independent afterwards

  const float* urA = u + (size_t)rowA * NS;
  const float* urB = u + (size_t)rowB * NS;
  int* orA = out + (size_t)rowA * NS;
  int* orB = out + (size_t)rowB * NS;

  f32x2 h2 = {0.0f, 0.0f};
  int prevA = 0, prevB = 0;
  hp[wv][lane] = h2;
  const f32x4* hp4 = (const f32x4*)&hp[wv][0];

  for (int c = 0; c < 16; ++c) {
    float uA = urA[c * 64 + lane];
    float uB = urB[c * 64 + lane];
    int mybitA = 0, mybitB = 0;
    for (int tt = 0; tt < 64; ++tt) {
      // gh = h @ w_hh.T for both rows, packed: per-component sequential-k
      // FMA chain from 0 (Eigen gebp clone, components independent).
      // FULL unroll: all wr2[] indices compile-time (keeps wr2 in registers).
      f32x2 ar2 = {0.0f, 0.0f}, az2 = {0.0f, 0.0f}, an2 = {0.0f, 0.0f};
#pragma unroll
      for (int kk = 0; kk < 32; ++kk) {
        f32x4 h4 = hp4[kk];            // uniform b128: pairs for k=2kk, 2kk+1
        f32x4 w4 = wzn[kk][lane];      // lane-contiguous b128
        f32x2 h2a = __builtin_shufflevector(h4, h4, 0, 1);
        f32x2 h2b = __builtin_shufflevector(h4, h4, 2, 3);
        f32x2 wa = __builtin_shufflevector(w4, w4, 0, 1);  // (wz,wn) @ 2kk
        f32x2 wb = __builtin_shufflevector(w4, w4, 2, 3);  // (wz,wn) @ 2kk+1
        PKFMA_LO(ar2, h2a, wr2[kk]);   // += h * wr[2kk]
        PKFMA_LO(az2, h2a, wa);        // += h * wz[2kk]
        PKFMA_HI(an2, h2a, wa);        // += h * wn[2kk]
        PKFMA_HI(ar2, h2b, wr2[kk]);   // += h * wr[2kk+1]
        PKFMA_LO(az2, h2b, wb);        // += h * wz[2kk+1]
        PKFMA_HI(an2, h2b, wb);        // += h * wn[2kk+1]
      }
      // gates, exact reference association (packed mul/add are unfused)
      f32x2 ghr2 = ar2 + bhh_r;
      f32x2 ghz2 = az2 + bhh_z;
      f32x2 ghn2 = an2 + bhh_n;
      f32x2 gxr2 = {prevA ? sum_r : bih_r, prevB ? sum_r : bih_r};
      f32x2 gxz2 = {prevA ? sum_z : bih_z, prevB ? sum_z : bih_z};
      f32x2 gxn2 = {prevA ? sum_n : bih_n, prevB ? sum_n : bih_n};
      f32x2 r2 = xsigmoid2(gxr2 + ghr2);
      f32x2 z2 = xsigmoid2(gxz2 + ghz2);
      f32x2 n2 = xtanh2(gxn2 + r2 * ghn2);
      f32x2 omz = 1.0f - z2;           // (1-z): subrev, exact
      h2 = omz * n2 + z2 * h2;         // two muls + add, unfused = clone
      hp[wv][lane] = h2;               // for next step's matvec

      // head gemv clone: width-16 chunks then halving tree (per component)
      f32x2 P2 = h2 * hw2;
      f32x2 t, s2;
      t.x = __shfl(P2.x, lane + 16); t.y = __shfl(P2.y, lane + 16);
      s2 = P2 + t;
      t.x = __shfl(P2.x, lane + 32); t.y = __shfl(P2.y, lane + 32);
      s2 = s2 + t;
      t.x = __shfl(P2.x, lane + 48); t.y = __shfl(P2.y, lane + 48);
      s2 = s2 + t;
      t.x = __shfl(s2.x, lane + 8); t.y = __shfl(s2.y, lane + 8);
      s2 = s2 + t;
      t.x = __shfl(s2.x, lane + 4); t.y = __shfl(s2.y, lane + 4);
      s2 = s2 + t;
      t.x = __shfl(s2.x, lane + 2); t.y = __shfl(s2.y, lane + 2);
      s2 = s2 + t;
      t.x = __shfl(s2.x, lane + 1); t.y = __shfl(s2.y, lane + 1);
      s2 = s2 + t;
      float logitA = __fadd_rn(rdlane(s2.x, 0), hb);
      float logitB = __fadd_rn(rdlane(s2.y, 0), hb);
      f32x2 p2 = xsigmoid2(f32x2{logitA, logitB});

      float uAt = rdlane(uA, tt);
      float uBt = rdlane(uB, tt);
      int bA = (uAt < p2.x) ? 1 : 0;
      int bB = (uBt < p2.y) ? 1 : 0;
      prevA = bA;
      prevB = bB;
      mybitA = (lane == tt) ? bA : mybitA;
      mybitB = (lane == tt) ? bB : mybitB;
    }
    orA[c * 64 + lane] = mybitA;
    orB[c * 64 + lane] = mybitB;
  }
}

extern "C" void kernel_launch(void* const* d_in, const int* in_sizes, int n_in,
                              void* d_out, int out_size, void* d_ws, size_t ws_size,
                              hipStream_t stream) {
  const float* u = (const float*)d_in[0];
  const float* w_ih = (const float*)d_in[1];
  const float* w_hh = (const float*)d_in[2];
  const float* b_ih = (const float*)d_in[3];
  const float* b_hh = (const float*)d_in[4];
  const float* head_w = (const float*)d_in[5];
  const float* head_b = (const float*)d_in[6];
  int* out = (int*)d_out;
  dim3 grid(NB / 8), block(256);
  gru_sample_kernel<<<grid, block, 0, stream>>>(u, w_ih, w_hh, b_ih, b_hh,
                                                head_w, head_b, out);
}

// Round 10
// 8663.179 us; speedup vs baseline: 7.6845x; 1.0216x over previous
//
#include <hip/hip_runtime.h>

#define NS 1024
#define NH 64
#define NB 16384

typedef float f32x2 __attribute__((ext_vector_type(2)));
typedef float f32x4 __attribute__((ext_vector_type(4)));

// Disable FP contraction file-wide: vector a*b+c must stay mul+add (XLA-CPU
// has no contraction). Explicit inline-asm pk_fma used where fma is intended.
#pragma clang fp contract(off)

// v_pk_fma_f32 with src1 broadcast from one register of its 64-bit pair.
// op_sel selects the source register for the LOW result half, op_sel_hi for
// the HIGH half (bits are [src0, src1, src2]).
// PKFMA_LO: both halves use w.lo ; PKFMA_HI: both halves use w.hi.
// (Semantics HW-verified: R7/R8/R9 passed with absmax 0.0.)
#define PKFMA_LO(acc, h, w)                                                  \
  asm("v_pk_fma_f32 %0, %1, %2, %0 op_sel:[0,0,0] op_sel_hi:[1,0,1]"         \
      : "+v"(acc) : "v"(h), "v"(w))
#define PKFMA_HI(acc, h, w)                                                  \
  asm("v_pk_fma_f32 %0, %1, %2, %0 op_sel:[0,1,0] op_sel_hi:[1,1,1]"         \
      : "+v"(acc) : "v"(h), "v"(w))

// ---- XLA-CPU fp32 op clones, packed over (rowA,rowB); per-component ops
// identical to the verified scalar clone (mul/add unfused, IEEE div). ----

__device__ __forceinline__ f32x2 xexp2v(f32x2 x) {
  x = __builtin_elementwise_min(x, f32x2{88.3762626647950f, 88.3762626647950f});
  x = __builtin_elementwise_max(x, f32x2{-88.3762626647949f, -88.3762626647949f});
  f32x2 fx = __builtin_elementwise_floor(x * 1.44269504088896341f + 0.5f);
  x = x - fx * 0.693359375f;
  x = x - fx * (-2.12194440e-4f);
  f32x2 z = x * x;
  f32x2 y = {1.9875691500e-4f, 1.9875691500e-4f};
  y = y * x + 1.3981999507e-3f;
  y = y * x + 8.3334519073e-3f;
  y = y * x + 4.1665795894e-2f;
  y = y * x + 1.6666665459e-1f;
  y = y * x + 5.0000001201e-1f;
  y = y * z + x;
  y = y + 1.0f;
  int n0 = (int)fx.x, n1 = (int)fx.y;
  float p0 = __int_as_float((n0 + 127) << 23);
  float p1 = __int_as_float((n1 + 127) << 23);
  f32x2 r;
  r.x = __fmul_rn(y.x, p0);
  r.y = __fmul_rn(y.y, p1);
  return r;
}

__device__ __forceinline__ f32x2 xsigmoid2(f32x2 x) {
  f32x2 e = xexp2v(-x);
  f32x2 d = e + 1.0f;
  f32x2 r;
  r.x = __fdiv_rn(1.0f, d.x);
  r.y = __fdiv_rn(1.0f, d.y);
  return r;
}

__device__ __forceinline__ f32x2 xtanh2(f32x2 x) {
  f32x2 xc = __builtin_elementwise_min(
      __builtin_elementwise_max(x, f32x2{-7.90531110763549805f, -7.90531110763549805f}),
      f32x2{7.90531110763549805f, 7.90531110763549805f});
  f32x2 s = xc * xc;
  f32x2 p = {-2.76076847742355e-16f, -2.76076847742355e-16f};
  p = p * s + 2.00018790482477e-13f;
  p = p * s + (-8.60467152213735e-11f);
  p = p * s + 5.12229709037114e-08f;
  p = p * s + 1.48572235717979e-05f;
  p = p * s + 6.37261928875436e-04f;
  p = p * s + 4.89352455891786e-03f;
  f32x2 num = xc * p;
  f32x2 q = {1.19825839466702e-06f, 1.19825839466702e-06f};
  q = q * s + 1.18534705686654e-04f;
  q = q * s + 2.26843463243900e-03f;
  q = q * s + 4.89352518554385e-03f;
  f32x2 rat;
  rat.x = __fdiv_rn(num.x, q.x);
  rat.y = __fdiv_rn(num.y, q.y);
  f32x2 r;
  r.x = (fabsf(x.x) < 0.0004f) ? x.x : rat.x;
  r.y = (fabsf(x.y) < 0.0004f) ? x.y : rat.y;
  return r;
}

__device__ __forceinline__ float rdlane(float v, int l) {
  return __int_as_float(__builtin_amdgcn_readlane(__float_as_int(v), l));
}

// 4 waves/block, TWO rows per wave via packed FP32 (v_pk_fma_f32): lane j
// owns hidden unit j for rows A,B. w_r in VGPRs as 32 f32x2 pairs; w_z,w_n
// interleaved in LDS (one 32KB copy/block); h stored as (hA,hB) pairs.
//
// R8/R9 lesson: with the kk-loop fully unrolled and unfenced, the pre-RA
// scheduler hoists all 64 ds_read transients (~256 regs pressure) and the
// RA demotes wr2 to AGPRs (v_accvgpr_read on every use, combined ~200 regs,
// 10 waves/CU). Fix: sched_barrier(0) every 2 kk caps peak pressure at
// ~126 <= the 128-arch-VGPR cap from launch_bounds(256,2) -> all-VGPR,
// zero AGPR tax, occupancy rises to the LDS cap (16 waves/CU).
__global__ __launch_bounds__(256, 2) void gru_sample_kernel(
    const float* __restrict__ u, const float* __restrict__ w_ih,
    const float* __restrict__ w_hh, const float* __restrict__ b_ih,
    const float* __restrict__ b_hh, const float* __restrict__ head_w,
    const float* __restrict__ head_b, int* __restrict__ out) {
  const int lane = threadIdx.x & 63;
  const int wv = threadIdx.x >> 6;  // 0..3
  const int rowA = blockIdx.x * 8 + wv * 2;
  const int rowB = rowA + 1;

  __shared__ f32x4 wzn[32][NH];   // [kk][j] = (wz[2kk], wn[2kk], wz[2kk+1], wn[2kk+1]) of unit j
  __shared__ f32x2 hp[4][NH];     // [wave][k] = (hA[k], hB[k])

  // Cooperative weight fill (one-time).
  for (int idx = threadIdx.x; idx < 32 * NH; idx += 256) {
    int kk = idx & 31, j = idx >> 5;
    const float* wzrow = w_hh + (size_t)(64 + j) * NH;
    const float* wnrow = w_hh + (size_t)(128 + j) * NH;
    wzn[kk][j] = f32x4{wzrow[2 * kk], wnrow[2 * kk], wzrow[2 * kk + 1], wnrow[2 * kk + 1]};
  }
  // r-gate weights in registers as pairs (wr[2i], wr[2i+1]).
  f32x2 wr2[32];
#pragma unroll
  for (int i = 0; i < 32; ++i)
    wr2[i] = *(const f32x2*)&w_hh[(size_t)lane * NH + 2 * i];

  const float bih_r = b_ih[lane], bih_z = b_ih[64 + lane], bih_n = b_ih[128 + lane];
  const float bhh_r = b_hh[lane], bhh_z = b_hh[64 + lane], bhh_n = b_hh[128 + lane];
  // prev ∈ {0,1}: gx = prev*w_ih + b_ih == (prev ? w_ih+b_ih : b_ih) bit-exactly.
  const float sum_r = __fadd_rn(w_ih[lane], bih_r);
  const float sum_z = __fadd_rn(w_ih[64 + lane], bih_z);
  const float sum_n = __fadd_rn(w_ih[128 + lane], bih_n);
  const float hwv = head_w[lane];
  const f32x2 hw2 = {hwv, hwv};
  const float hb = head_b[0];
  __syncthreads();  // weights ready; waves independent afterwards

  const float* urA = u + (size_t)rowA * NS;
  const float* urB = u + (size_t)rowB * NS;
  int* orA = out + (size_t)rowA * NS;
  int* orB = out + (size_t)rowB * NS;

  f32x2 h2 = {0.0f, 0.0f};
  int prevA = 0, prevB = 0;
  hp[wv][lane] = h2;
  const f32x4* hp4 = (const f32x4*)&hp[wv][0];

  for (int c = 0; c < 16; ++c) {
    float uA = urA[c * 64 + lane];
    float uB = urB[c * 64 + lane];
    int mybitA = 0, mybitB = 0;
    for (int tt = 0; tt < 64; ++tt) {
      // gh = h @ w_hh.T for both rows, packed: per-component sequential-k
      // FMA chain from 0 (Eigen gebp clone, components independent).
      // sched_barrier(0) every 2 kk: caps scheduler load-hoisting so peak
      // register pressure stays under the 128-arch-VGPR cap (no AGPR tax).
      f32x2 ar2 = {0.0f, 0.0f}, az2 = {0.0f, 0.0f}, an2 = {0.0f, 0.0f};
#pragma unroll
      for (int kk = 0; kk < 32; ++kk) {
        f32x4 h4 = hp4[kk];            // uniform b128: pairs for k=2kk, 2kk+1
        f32x4 w4 = wzn[kk][lane];      // lane-contiguous b128
        f32x2 h2a = __builtin_shufflevector(h4, h4, 0, 1);
        f32x2 h2b = __builtin_shufflevector(h4, h4, 2, 3);
        f32x2 wa = __builtin_shufflevector(w4, w4, 0, 1);  // (wz,wn) @ 2kk
        f32x2 wb = __builtin_shufflevector(w4, w4, 2, 3);  // (wz,wn) @ 2kk+1
        PKFMA_LO(ar2, h2a, wr2[kk]);   // += h * wr[2kk]
        PKFMA_LO(az2, h2a, wa);        // += h * wz[2kk]
        PKFMA_HI(an2, h2a, wa);        // += h * wn[2kk]
        PKFMA_HI(ar2, h2b, wr2[kk]);   // += h * wr[2kk+1]
        PKFMA_LO(az2, h2b, wb);        // += h * wz[2kk+1]
        PKFMA_HI(an2, h2b, wb);        // += h * wn[2kk+1]
        if ((kk & 1) == 1) __builtin_amdgcn_sched_barrier(0);
      }
      // gates, exact reference association (packed mul/add are unfused)
      f32x2 ghr2 = ar2 + bhh_r;
      f32x2 ghz2 = az2 + bhh_z;
      f32x2 ghn2 = an2 + bhh_n;
      f32x2 gxr2 = {prevA ? sum_r : bih_r, prevB ? sum_r : bih_r};
      f32x2 gxz2 = {prevA ? sum_z : bih_z, prevB ? sum_z : bih_z};
      f32x2 gxn2 = {prevA ? sum_n : bih_n, prevB ? sum_n : bih_n};
      f32x2 r2 = xsigmoid2(gxr2 + ghr2);
      f32x2 z2 = xsigmoid2(gxz2 + ghz2);
      f32x2 n2 = xtanh2(gxn2 + r2 * ghn2);
      f32x2 omz = 1.0f - z2;           // (1-z): subrev, exact
      h2 = omz * n2 + z2 * h2;         // two muls + add, unfused = clone
      hp[wv][lane] = h2;               // for next step's matvec

      // head gemv clone: width-16 chunks then halving tree (per component)
      f32x2 P2 = h2 * hw2;
      f32x2 t, s2;
      t.x = __shfl(P2.x, lane + 16); t.y = __shfl(P2.y, lane + 16);
      s2 = P2 + t;
      t.x = __shfl(P2.x, lane + 32); t.y = __shfl(P2.y, lane + 32);
      s2 = s2 + t;
      t.x = __shfl(P2.x, lane + 48); t.y = __shfl(P2.y, lane + 48);
      s2 = s2 + t;
      t.x = __shfl(s2.x, lane + 8); t.y = __shfl(s2.y, lane + 8);
      s2 = s2 + t;
      t.x = __shfl(s2.x, lane + 4); t.y = __shfl(s2.y, lane + 4);
      s2 = s2 + t;
      t.x = __shfl(s2.x, lane + 2); t.y = __shfl(s2.y, lane + 2);
      s2 = s2 + t;
      t.x = __shfl(s2.x, lane + 1); t.y = __shfl(s2.y, lane + 1);
      s2 = s2 + t;
      float logitA = __fadd_rn(rdlane(s2.x, 0), hb);
      float logitB = __fadd_rn(rdlane(s2.y, 0), hb);
      f32x2 p2 = xsigmoid2(f32x2{logitA, logitB});

      float uAt = rdlane(uA, tt);
      float uBt = rdlane(uB, tt);
      int bA = (uAt < p2.x) ? 1 : 0;
      int bB = (uBt < p2.y) ? 1 : 0;
      prevA = bA;
      prevB = bB;
      mybitA = (lane == tt) ? bA : mybitA;
      mybitB = (lane == tt) ? bB : mybitB;
    }
    orA[c * 64 + lane] = mybitA;
    orB[c * 64 + lane] = mybitB;
  }
}

extern "C" void kernel_launch(void* const* d_in, const int* in_sizes, int n_in,
                              void* d_out, int out_size, void* d_ws, size_t ws_size,
                              hipStream_t stream) {
  const float* u = (const float*)d_in[0];
  const float* w_ih = (const float*)d_in[1];
  const float* w_hh = (const float*)d_in[2];
  const float* b_ih = (const float*)d_in[3];
  const float* b_hh = (const float*)d_in[4];
  const float* head_w = (const float*)d_in[5];
  const float* head_b = (const float*)d_in[6];
  int* out = (int*)d_out;
  dim3 grid(NB / 8), block(256);
  gru_sample_kernel<<<grid, block, 0, stream>>>(u, w_ih, w_hh, b_ih, b_hh,
                                                head_w, head_b, out);
}